// Round 1
// baseline (815.192 us; speedup 1.0000x reference)
//
#include <hip/hip_runtime.h>
#include <math.h>

#ifndef M_PI
#define M_PI 3.14159265358979323846
#endif

// ---- problem constants ----
#define BB 4
#define TT 4
#define NSEM 16
#define CHL 22            // NC + NUM_SEM
#define CHMF 28           // NC + NC + NUM_SEM
#define ML 240
#define MG 960
#define VR 100
#define HS 120            // FRAME_H/DU
#define WSW 160           // FRAME_W/DU
#define NPL 18            // planes: 0=agent_hp[0], 1=all_hp[0], 2..17=agent_hp[1..16]
#define MLSQ (ML*ML)      // 57600
#define MGSQ (MG*MG)      // 921600
#define VRSQ (VR*VR)      // 10000

// ---- output layout (floats) ----
#define SZ_MF (BB*TT*CHMF*MLSQ)
#define SZ_FL (BB*CHL*MLSQ)
#define SZ_FG (BB*CHL*MGSQ)
#define OFF_FL SZ_MF
#define OFF_FG (OFF_FL + SZ_FL)
#define OFF_LP (OFF_FG + SZ_FG)
#define OFF_GP (OFF_LP + BB*TT*3)
#define OFF_LMB (OFF_GP + BB*TT*3)
#define OFF_ORG (OFF_LMB + BB*TT*4)

// ---- ws layout (floats) ----
#define WS_SCAL 0                         // B*8: cos,sin,stx,sty,acx,acy
#define WS_POSE 32                        // B*3 pose state
#define WS_PLANES 64                      // B*18*100*100 = 720000
#define WS_I1 (WS_PLANES + BB*NPL*VRSQ)   // B*18*240*240
#define WS_I2 (WS_I1 + BB*NPL*MLSQ)

// once per call: seq_lmb / seq_org outputs + pose state init
__global__ void k_init(const float* __restrict__ ilp, const float* __restrict__ org,
                       const int* __restrict__ lmb, float* __restrict__ out,
                       float* __restrict__ ws)
{
    int i = threadIdx.x;
    if (i < BB*TT) {
        int b = i / TT, t = i % TT;
        for (int k = 0; k < 4; k++) out[OFF_LMB + (b*TT+t)*4 + k] = (float)lmb[b*4+k];
        for (int k = 0; k < 3; k++) out[OFF_ORG + (b*TT+t)*3 + k] = org[b*3+k];
    }
    if (i < BB) {
        for (int k = 0; k < 3; k++) ws[WS_POSE + i*3 + k] = ilp[i*3+k];
    }
}

// per step: pose update + per-batch affine scalars
__global__ void k_pose(const float* __restrict__ pd, const float* __restrict__ org,
                       const int* __restrict__ dones, float* __restrict__ out,
                       float* __restrict__ ws, int t)
{
    int b = threadIdx.x;
    if (b >= BB) return;
    float p0 = ws[WS_POSE+b*3+0], p1 = ws[WS_POSE+b*3+1], p2 = ws[WS_POSE+b*3+2];
    if (dones[b*TT+t]) { p0 = 6.0f; p1 = 6.0f; p2 = 0.0f; }   // CENTER_POSE=6
    const float D2R = 0.017453292519943295f;
    float tr = p2 * D2R;
    float c0 = cosf(tr), s0 = sinf(tr);
    float q0 = pd[(b*TT+t)*3+0], q1 = pd[(b*TT+t)*3+1], q2 = pd[(b*TT+t)*3+2];
    float nx = p0 + q0*c0 - q1*s0;
    float ny = p1 + q0*s0 + q1*c0;
    float a  = p2 + q2*57.29577951308232f + 180.0f;
    float m  = fmodf(a, 360.0f); if (m < 0.0f) m += 360.0f;   // jnp.mod semantics
    float nt = m - 180.0f;
    ws[WS_POSE+b*3+0] = nx; ws[WS_POSE+b*3+1] = ny; ws[WS_POSE+b*3+2] = nt;
    out[OFF_LP + (b*TT+t)*3+0] = nx;
    out[OFF_LP + (b*TT+t)*3+1] = ny;
    out[OFF_LP + (b*TT+t)*3+2] = nt;
    out[OFF_GP + (b*TT+t)*3+0] = nx + org[b*3+0];
    out[OFF_GP + (b*TT+t)*3+1] = ny + org[b*3+1];
    out[OFF_GP + (b*TT+t)*3+2] = nt + org[b*3+2];
    float th = (90.0f - nt) * D2R;
    float ax = nx*100.0f/5.0f, ay = ny*100.0f/5.0f;
    ws[WS_SCAL+b*8+0] = cosf(th);
    ws[WS_SCAL+b*8+1] = sinf(th);
    ws[WS_SCAL+b*8+2] = -(ax - 120.0f)/120.0f;
    ws[WS_SCAL+b*8+3] = -(ay - 120.0f)/120.0f;
    ws[WS_SCAL+b*8+4] = ax;
    ws[WS_SCAL+b*8+5] = ay;
}

// conditional map resets on done (grid-stride; near-free when not done)
__global__ __launch_bounds__(256) void k_rstl(float* __restrict__ fl,
                                              const int* __restrict__ dones, int t)
{
    int b = blockIdx.y;
    if (!dones[b*TT+t]) return;
    float* p = fl + (size_t)b*CHL*MLSQ;
    for (int idx = blockIdx.x*256 + threadIdx.x; idx < CHL*MLSQ; idx += gridDim.x*256)
        p[idx] = 0.0f;
}
__global__ __launch_bounds__(256) void k_rstg(float* __restrict__ fg,
                                              const int* __restrict__ dones, int t)
{
    int b = blockIdx.y;
    if (!dones[b*TT+t]) return;
    float* p = fg + (size_t)b*CHL*MGSQ;
    for (size_t idx = blockIdx.x*256 + threadIdx.x; idx < (size_t)CHL*MGSQ;
         idx += (size_t)gridDim.x*256)
        p[idx] = 0.0f;
}

// depth -> points, sem 4x4 mean, trilinear splat (z pre-collapsed) into planes
__global__ __launch_bounds__(256) void k_splat(const float* __restrict__ obs,
                                               const float* __restrict__ cam,
                                               float* __restrict__ planes, int t)
{
    int b = blockIdx.y;
    int p = blockIdx.x*256 + threadIdx.x;            // < 19200
    int h = p / WSW, w = p % WSW;
    const float* ob = obs + (size_t)(b*TT + t) * 20 * 480 * 640;
    float d = ob[(size_t)(3*480 + 4*h)*640 + 4*w];
    if (!(d >= 50.0f && d <= 350.0f)) return;

    double fd = 640.0 / (2.0 * tan((79.0 * M_PI / 180.0) * 0.5));
    float ff  = (float)fd;
    float xsv = (float)(4*w - 320) / ff;
    float zrv = (240.0f - (float)(4*h)) / ff;
    float elev = atan2f(cam[b*16+9], cam[b*16+10]);
    float ce = cosf(elev), se = sinf(elev);
    float up  = d * zrv;
    float fwd = d*ce + up*se;
    float hgt = -d*se + up*ce + 88.0f;
    float gx = (d*xsv)/5.0f + 50.0f;
    float gy = fwd/5.0f;
    float gz = hgt/5.0f + 8.0f;                      // - ZMIN

    // semantic 4x4 means (exact: integer sums / 16)
    float sem[NSEM];
    const float* sb = ob + (size_t)4*480*640 + (size_t)(4*h)*640 + 4*w;
    #pragma unroll
    for (int k = 0; k < NSEM; k++) {
        float s = 0.0f;
        #pragma unroll
        for (int r = 0; r < 4; r++) {
            const float4 v = *(const float4*)(sb + (size_t)k*480*640 + r*640);
            s += v.x + v.y + v.z + v.w;
        }
        sem[k] = s * 0.0625f;
    }

    float x0 = floorf(gx), y0 = floorf(gy), z0 = floorf(gz);
    float wza = 0.0f, wzl = 0.0f;                    // agent-window / all-z weights
    #pragma unroll
    for (int dz = 0; dz < 2; dz++) {
        float zi = z0 + dz;
        float wz = 1.0f - fabsf(gz - zi);
        if (zi >= 0.0f && zi < 80.0f) {
            wzl += wz;
            if (zi >= 13.0f && zi < 25.0f) wza += wz;   // MIN_MAP_H..MAX_MAP_H
        }
    }
    if (wzl == 0.0f && wza == 0.0f) return;

    float* pl = planes + (size_t)b*NPL*VRSQ;
    #pragma unroll
    for (int dy = 0; dy < 2; dy++) {
        float yi = y0 + dy;
        if (!(yi >= 0.0f && yi < 100.0f)) continue;
        float wy = 1.0f - fabsf(gy - yi);
        #pragma unroll
        for (int dx = 0; dx < 2; dx++) {
            float xi = x0 + dx;
            if (!(xi >= 0.0f && xi < 100.0f)) continue;
            float wxy = (1.0f - fabsf(gx - xi)) * wy;
            if (wxy <= 0.0f) continue;
            int cell = (int)yi * VR + (int)xi;
            if (wza > 0.0f) {
                atomicAdd(pl + cell, wza*wxy);
                #pragma unroll
                for (int k = 0; k < NSEM; k++) {
                    float sv = sem[k];
                    if (sv != 0.0f) atomicAdd(pl + (2+k)*VRSQ + cell, sv*wza*wxy);
                }
            }
            if (wzl > 0.0f) atomicAdd(pl + VRSQ + cell, wzl*wxy);
        }
    }
}

// grid_sample #1 (rotation) sampling clipped planes placed at [120:220,70:170)
__global__ __launch_bounds__(256) void k_gs1(const float* __restrict__ planes,
                                             const float* __restrict__ ws,
                                             float* __restrict__ I1)
{
    int b = blockIdx.z, pc = blockIdx.y;
    int idx = blockIdx.x*256 + threadIdx.x;
    int i = idx / ML, j = idx % ML;
    float c = ws[WS_SCAL + b*8 + 0], s = ws[WS_SCAL + b*8 + 1];
    float xg = (float)j * (float)(2.0/239.0) - 1.0f;
    float yg = (float)i * (float)(2.0/239.0) - 1.0f;
    float gxr = c*xg - s*yg;
    float gyr = s*xg + c*yg;
    float x = (gxr + 1.0f)*0.5f*239.0f;
    float y = (gyr + 1.0f)*0.5f*239.0f;
    float x0 = floorf(x), y0 = floorf(y);
    float acc = 0.0f;
    const float* pl = planes + ((size_t)b*NPL + pc)*VRSQ;
    bool issem = (pc >= 2);
    #pragma unroll
    for (int dy = 0; dy < 2; dy++) {
        float yi = y0 + dy;
        if (!(yi >= 120.0f && yi < 220.0f)) continue;
        float wy = 1.0f - fabsf(y - yi);
        #pragma unroll
        for (int dx = 0; dx < 2; dx++) {
            float xi = x0 + dx;
            if (!(xi >= 70.0f && xi < 170.0f)) continue;
            float v = pl[((int)yi - 120)*VR + ((int)xi - 70)];
            if (issem) v = v / 5.0f;                 // CAT_THR
            v = fminf(v, 1.0f);                      // clip (v >= 0)
            acc += v * ((1.0f - fabsf(x - xi)) * wy);
        }
    }
    I1[((size_t)b*NPL + pc)*MLSQ + idx] = acc;
}

// grid_sample #2 (translation) over full I1 with zeros padding
__global__ __launch_bounds__(256) void k_gs2(const float* __restrict__ I1,
                                             const float* __restrict__ ws,
                                             float* __restrict__ I2)
{
    int b = blockIdx.z, pc = blockIdx.y;
    int idx = blockIdx.x*256 + threadIdx.x;
    int i = idx / ML, j = idx % ML;
    float stx = ws[WS_SCAL + b*8 + 2], sty = ws[WS_SCAL + b*8 + 3];
    float xg = (float)j * (float)(2.0/239.0) - 1.0f + stx;
    float yg = (float)i * (float)(2.0/239.0) - 1.0f + sty;
    float x = (xg + 1.0f)*0.5f*239.0f;
    float y = (yg + 1.0f)*0.5f*239.0f;
    float x0 = floorf(x), y0 = floorf(y);
    float acc = 0.0f;
    const float* src = I1 + ((size_t)b*NPL + pc)*MLSQ;
    #pragma unroll
    for (int dy = 0; dy < 2; dy++) {
        float yi = y0 + dy;
        if (!(yi >= 0.0f && yi <= 239.0f)) continue;
        float wy = 1.0f - fabsf(y - yi);
        #pragma unroll
        for (int dx = 0; dx < 2; dx++) {
            float xi = x0 + dx;
            if (!(xi >= 0.0f && xi <= 239.0f)) continue;
            acc += src[(int)yi*ML + (int)xi] * ((1.0f - fabsf(x - xi)) * wy);
        }
    }
    I2[((size_t)b*NPL + pc)*MLSQ + idx] = acc;
}

// 3x3 maxpool(ch0) + max-merge into local map + agent disks (ch 2/3/4)
__global__ __launch_bounds__(256) void k_updl(const float* __restrict__ I2,
                                              const float* __restrict__ ws,
                                              float* __restrict__ fl)
{
    int b = blockIdx.y;
    int idx = blockIdx.x*256 + threadIdx.x;
    int i = idx / ML, j = idx % ML;
    const float* src = I2 + (size_t)b*NPL*MLSQ;
    float m = -3.0e38f;
    for (int di = -1; di <= 1; di++) {
        int ii = i + di; if (ii < 0 || ii >= ML) continue;
        for (int dj = -1; dj <= 1; dj++) {
            int jj = j + dj; if (jj < 0 || jj >= ML) continue;
            m = fmaxf(m, src[ii*ML + jj]);
        }
    }
    float* lm = fl + (size_t)b*CHL*MLSQ;
    lm[idx]        = fmaxf(lm[idx], m);
    lm[MLSQ + idx] = fmaxf(lm[MLSQ + idx], src[MLSQ + idx]);
    #pragma unroll
    for (int k = 0; k < NSEM; k++)
        lm[(6+k)*MLSQ + idx] = fmaxf(lm[(6+k)*MLSQ + idx], src[(2+k)*MLSQ + idx]);
    float acx = ws[WS_SCAL+b*8+4], acy = ws[WS_SCAL+b*8+5];
    float ddx = (float)j - acx, ddy = (float)i - acy;
    float d2 = ddx*ddx + ddy*ddy;
    float curr = (d2 <= 4.0f) ? 1.0f : 0.0f;
    lm[2*MLSQ + idx] = curr;
    lm[3*MLSQ + idx] = fmaxf(lm[3*MLSQ + idx], curr);
    lm[4*MLSQ + idx] = fmaxf(lm[4*MLSQ + idx], (d2 <= 1600.0f) ? 1.0f : 0.0f);
}

// conditional global-map window write
__global__ __launch_bounds__(256) void k_gupd(const float* __restrict__ fl,
                                              float* __restrict__ fg,
                                              const int* __restrict__ upd,
                                              const int* __restrict__ lmb, int t)
{
    int b = blockIdx.z;
    if (!upd[b*TT + t]) return;
    int c = blockIdx.y;
    int idx = blockIdx.x*256 + threadIdx.x;
    int i = idx / ML, j = idx % ML;
    int y0 = lmb[b*4+0], x0 = lmb[b*4+2];
    fg[((size_t)b*CHL + c)*MGSQ + (size_t)(y0+i)*MG + (x0+j)] =
        fl[((size_t)b*CHL + c)*MLSQ + idx];
}

// emit 28-channel map_features for step t (gmax = 4x4 max of global ch0..5)
__global__ __launch_bounds__(256) void k_mf(const float* __restrict__ fl,
                                            const float* __restrict__ fg,
                                            float* __restrict__ out, int t)
{
    int b = blockIdx.y;
    int idx = blockIdx.x*256 + threadIdx.x;
    int i = idx / ML, j = idx % ML;
    const float* lm = fl + (size_t)b*CHL*MLSQ;
    float* mf = out + (size_t)(b*TT + t)*CHMF*MLSQ;
    #pragma unroll
    for (int c = 0; c < 6; c++) mf[c*MLSQ + idx] = lm[c*MLSQ + idx];
    #pragma unroll
    for (int c = 0; c < 6; c++) {
        const float* g = fg + ((size_t)b*CHL + c)*MGSQ + (size_t)(4*i)*MG + 4*j;
        float m = -3.0e38f;
        #pragma unroll
        for (int r = 0; r < 4; r++) {
            float4 q = *(const float4*)(g + (size_t)r*MG);
            m = fmaxf(m, fmaxf(fmaxf(q.x, q.y), fmaxf(q.z, q.w)));
        }
        mf[(6+c)*MLSQ + idx] = m;
    }
    #pragma unroll
    for (int k = 0; k < NSEM; k++) mf[(12+k)*MLSQ + idx] = lm[(6+k)*MLSQ + idx];
}

extern "C" void kernel_launch(void* const* d_in, const int* in_sizes, int n_in,
                              void* d_out, int out_size, void* d_ws, size_t ws_size,
                              hipStream_t stream)
{
    const float* obs   = (const float*)d_in[0];
    const float* pd    = (const float*)d_in[1];
    const float* cam   = (const float*)d_in[2];
    const float* ilm   = (const float*)d_in[3];
    const float* igm   = (const float*)d_in[4];
    const float* ilp   = (const float*)d_in[5];
    const float* org   = (const float*)d_in[7];
    const int*   dones = (const int*)d_in[8];
    const int*   updg  = (const int*)d_in[9];
    const int*   lmb   = (const int*)d_in[10];
    float* out = (float*)d_out;
    float* ws  = (float*)d_ws;

    float* fl     = out + OFF_FL;    // local map state lives in output
    float* fg     = out + OFF_FG;    // global map state lives in output
    float* planes = ws + WS_PLANES;
    float* I1v    = ws + WS_I1;
    float* I2v    = ws + WS_I2;

    hipMemcpyAsync(fl, ilm, (size_t)SZ_FL*sizeof(float), hipMemcpyDeviceToDevice, stream);
    hipMemcpyAsync(fg, igm, (size_t)SZ_FG*sizeof(float), hipMemcpyDeviceToDevice, stream);
    k_init<<<1, 64, 0, stream>>>(ilp, org, lmb, out, ws);

    for (int t = 0; t < TT; t++) {
        k_pose<<<1, 64, 0, stream>>>(pd, org, dones, out, ws, t);
        k_rstl<<<dim3(64, BB), 256, 0, stream>>>(fl, dones, t);
        k_rstg<<<dim3(512, BB), 256, 0, stream>>>(fg, dones, t);
        hipMemsetAsync(planes, 0, (size_t)BB*NPL*VRSQ*sizeof(float), stream);
        k_splat<<<dim3(75, BB), 256, 0, stream>>>(obs, cam, planes, t);
        k_gs1<<<dim3(225, NPL, BB), 256, 0, stream>>>(planes, ws, I1v);
        k_gs2<<<dim3(225, NPL, BB), 256, 0, stream>>>(I1v, ws, I2v);
        k_updl<<<dim3(225, BB), 256, 0, stream>>>(I2v, ws, fl);
        k_gupd<<<dim3(225, CHL, BB), 256, 0, stream>>>(fl, fg, updg, lmb, t);
        k_mf<<<dim3(225, BB), 256, 0, stream>>>(fl, fg, out, t);
    }
}

// Round 2
// 751.466 us; speedup vs baseline: 1.0848x; 1.0848x over previous
//
#include <hip/hip_runtime.h>
#include <math.h>

#ifndef M_PI
#define M_PI 3.14159265358979323846
#endif

// ---- problem constants ----
#define BB 4
#define TT 4
#define NSEM 16
#define CHL 22            // NC + NUM_SEM
#define CHMF 28           // NC + NC + NUM_SEM
#define ML 240
#define MG 960
#define VR 100
#define HS 120            // FRAME_H/DU
#define WSW 160           // FRAME_W/DU
#define NPL 18            // planes: 0=agent_hp[0], 1=all_hp[0], 2..17=agent_hp[1..16]
#define MLSQ (ML*ML)      // 57600
#define MGSQ (MG*MG)      // 921600
#define VRSQ (VR*VR)      // 10000

// ---- output layout (floats) ----
#define SZ_MF (BB*TT*CHMF*MLSQ)
#define SZ_FL (BB*CHL*MLSQ)
#define SZ_FG (BB*CHL*MGSQ)
#define OFF_FL SZ_MF
#define OFF_FG (OFF_FL + SZ_FL)
#define OFF_LP (OFF_FG + SZ_FG)
#define OFF_GP (OFF_LP + BB*TT*3)
#define OFF_LMB (OFF_GP + BB*TT*3)
#define OFF_ORG (OFF_LMB + BB*TT*4)

// ---- ws layout (floats) ----
#define WS_SCAL 0                                   // (b*TT+t)*8: c,s,stx,sty,acx,acy
#define WS_FLAGS (WS_SCAL + BB*TT*8)                // b*2: anyDone, zeroWin
#define WS_CACHE (WS_FLAGS + 2*BB)                  // B*6*240*240 gmax cache
#define WS_PLANES (WS_CACHE + BB*6*MLSQ)            // B*T*18*100*100
#define WS_I2 (WS_PLANES + BB*TT*NPL*VRSQ)          // B*T*18*240*240

// once: all T pose updates (sequential in t, parallel in b) + scalars + flags
__global__ void k_poseall(const float* __restrict__ pd, const float* __restrict__ ilp,
                          const float* __restrict__ org, const int* __restrict__ lmb,
                          const int* __restrict__ dones, const int* __restrict__ updg,
                          float* __restrict__ out, float* __restrict__ ws)
{
    int i = threadIdx.x;
    if (i < BB*TT) {
        int b = i / TT, t = i % TT;
        for (int k = 0; k < 4; k++) out[OFF_LMB + (b*TT+t)*4 + k] = (float)lmb[b*4+k];
        for (int k = 0; k < 3; k++) out[OFF_ORG + (b*TT+t)*3 + k] = org[b*3+k];
    }
    if (i >= BB) return;
    int b = i;
    float p0 = ilp[b*3+0], p1 = ilp[b*3+1], p2 = ilp[b*3+2];
    const float D2R = 0.017453292519943295f;
    int lastDone = -1, lastUpd = -1;
    for (int t = 0; t < TT; t++) {
        if (dones[b*TT+t]) { p0 = 6.0f; p1 = 6.0f; p2 = 0.0f; lastDone = t; }
        if (updg[b*TT+t]) lastUpd = t;
        float tr = p2 * D2R;
        float c0 = cosf(tr), s0 = sinf(tr);
        float q0 = pd[(b*TT+t)*3+0], q1 = pd[(b*TT+t)*3+1], q2 = pd[(b*TT+t)*3+2];
        float nx = p0 + q0*c0 - q1*s0;
        float ny = p1 + q0*s0 + q1*c0;
        float a  = p2 + q2*57.29577951308232f + 180.0f;
        float m  = fmodf(a, 360.0f); if (m < 0.0f) m += 360.0f;
        float nt = m - 180.0f;
        p0 = nx; p1 = ny; p2 = nt;
        out[OFF_LP + (b*TT+t)*3+0] = nx;
        out[OFF_LP + (b*TT+t)*3+1] = ny;
        out[OFF_LP + (b*TT+t)*3+2] = nt;
        out[OFF_GP + (b*TT+t)*3+0] = nx + org[b*3+0];
        out[OFF_GP + (b*TT+t)*3+1] = ny + org[b*3+1];
        out[OFF_GP + (b*TT+t)*3+2] = nt + org[b*3+2];
        float th = (90.0f - nt) * D2R;
        float ax = nx*100.0f/5.0f, ay = ny*100.0f/5.0f;
        float* sc = ws + WS_SCAL + (b*TT+t)*8;
        sc[0] = cosf(th);
        sc[1] = sinf(th);
        sc[2] = -(ax - 120.0f)/120.0f;
        sc[3] = -(ay - 120.0f)/120.0f;
        sc[4] = ax;
        sc[5] = ay;
    }
    ws[WS_FLAGS + b*2 + 0] = (lastDone >= 0) ? 1.0f : 0.0f;
    ws[WS_FLAGS + b*2 + 1] = (lastUpd < lastDone) ? 1.0f : 0.0f;
}

// all (b,t): depth -> points, sem 4x4 mean, trilinear splat (z pre-collapsed)
__global__ __launch_bounds__(256) void k_splat(const float* __restrict__ obs,
                                               const float* __restrict__ cam,
                                               float* __restrict__ planes)
{
    int bt = blockIdx.y;                             // b*TT + t
    int b = bt / TT;
    int p = blockIdx.x*256 + threadIdx.x;            // < 19200
    int h = p / WSW, w = p % WSW;
    const float* ob = obs + (size_t)bt * 20 * 480 * 640;
    float d = ob[(size_t)(3*480 + 4*h)*640 + 4*w];
    if (!(d >= 50.0f && d <= 350.0f)) return;

    double fd = 640.0 / (2.0 * tan((79.0 * M_PI / 180.0) * 0.5));
    float ff  = (float)fd;
    float xsv = (float)(4*w - 320) / ff;
    float zrv = (240.0f - (float)(4*h)) / ff;
    float elev = atan2f(cam[b*16+9], cam[b*16+10]);
    float ce = cosf(elev), se = sinf(elev);
    float up  = d * zrv;
    float fwd = d*ce + up*se;
    float hgt = -d*se + up*ce + 88.0f;
    float gx = (d*xsv)/5.0f + 50.0f;
    float gy = fwd/5.0f;
    float gz = hgt/5.0f + 8.0f;                      // - ZMIN

    float sem[NSEM];
    const float* sb = ob + (size_t)4*480*640 + (size_t)(4*h)*640 + 4*w;
    #pragma unroll
    for (int k = 0; k < NSEM; k++) {
        float s = 0.0f;
        #pragma unroll
        for (int r = 0; r < 4; r++) {
            const float4 v = *(const float4*)(sb + (size_t)k*480*640 + r*640);
            s += v.x + v.y + v.z + v.w;
        }
        sem[k] = s * 0.0625f;
    }

    float x0 = floorf(gx), y0 = floorf(gy), z0 = floorf(gz);
    float wza = 0.0f, wzl = 0.0f;
    #pragma unroll
    for (int dz = 0; dz < 2; dz++) {
        float zi = z0 + dz;
        float wz = 1.0f - fabsf(gz - zi);
        if (zi >= 0.0f && zi < 80.0f) {
            wzl += wz;
            if (zi >= 13.0f && zi < 25.0f) wza += wz;
        }
    }
    if (wzl == 0.0f && wza == 0.0f) return;

    float* pl = planes + (size_t)bt*NPL*VRSQ;
    #pragma unroll
    for (int dy = 0; dy < 2; dy++) {
        float yi = y0 + dy;
        if (!(yi >= 0.0f && yi < 100.0f)) continue;
        float wy = 1.0f - fabsf(gy - yi);
        #pragma unroll
        for (int dx = 0; dx < 2; dx++) {
            float xi = x0 + dx;
            if (!(xi >= 0.0f && xi < 100.0f)) continue;
            float wxy = (1.0f - fabsf(gx - xi)) * wy;
            if (wxy <= 0.0f) continue;
            int cell = (int)yi * VR + (int)xi;
            if (wza > 0.0f) {
                atomicAdd(pl + cell, wza*wxy);
                #pragma unroll
                for (int k = 0; k < NSEM; k++) {
                    float sv = sem[k];
                    if (sv != 0.0f) atomicAdd(pl + (2+k)*VRSQ + cell, sv*wza*wxy);
                }
            }
            if (wzl > 0.0f) atomicAdd(pl + VRSQ + cell, wzl*wxy);
        }
    }
}

// gs1 value at integer I1 pixel (ii,jj) — identical arithmetic to 2-pass version
__device__ __forceinline__ float gs1_tap(const float* __restrict__ pl, bool issem,
                                         float c, float s, int ii, int jj)
{
    float xg = (float)jj * (float)(2.0/239.0) - 1.0f;
    float yg = (float)ii * (float)(2.0/239.0) - 1.0f;
    float gxr = c*xg - s*yg;
    float gyr = s*xg + c*yg;
    float x = (gxr + 1.0f)*0.5f*239.0f;
    float y = (gyr + 1.0f)*0.5f*239.0f;
    float x0 = floorf(x), y0 = floorf(y);
    float acc = 0.0f;
    #pragma unroll
    for (int dy = 0; dy < 2; dy++) {
        float yi = y0 + dy;
        if (!(yi >= 120.0f && yi < 220.0f)) continue;
        float wy = 1.0f - fabsf(y - yi);
        #pragma unroll
        for (int dx = 0; dx < 2; dx++) {
            float xi = x0 + dx;
            if (!(xi >= 70.0f && xi < 170.0f)) continue;
            float v = pl[((int)yi - 120)*VR + ((int)xi - 70)];
            if (issem) v = v / 5.0f;
            v = fminf(v, 1.0f);
            acc += v * ((1.0f - fabsf(x - xi)) * wy);
        }
    }
    return acc;
}

// fused gs1∘gs2 for all (b,t): writes I2 directly (recomputes the 4 I1 taps)
__global__ __launch_bounds__(256) void k_gs(const float* __restrict__ planes,
                                            const float* __restrict__ ws,
                                            float* __restrict__ I2)
{
    int bt = blockIdx.z, pc = blockIdx.y;
    int idx = blockIdx.x*256 + threadIdx.x;
    int i = idx / ML, j = idx % ML;
    const float* sc = ws + WS_SCAL + bt*8;
    float c = sc[0], s = sc[1], stx = sc[2], sty = sc[3];
    float xg = (float)j * (float)(2.0/239.0) - 1.0f + stx;
    float yg = (float)i * (float)(2.0/239.0) - 1.0f + sty;
    float x = (xg + 1.0f)*0.5f*239.0f;
    float y = (yg + 1.0f)*0.5f*239.0f;
    float x0 = floorf(x), y0 = floorf(y);
    const float* pl = planes + ((size_t)bt*NPL + pc)*VRSQ;
    bool issem = (pc >= 2);
    float acc = 0.0f;
    #pragma unroll
    for (int dy = 0; dy < 2; dy++) {
        float yi = y0 + dy;
        if (!(yi >= 0.0f && yi <= 239.0f)) continue;
        float wy = 1.0f - fabsf(y - yi);
        #pragma unroll
        for (int dx = 0; dx < 2; dx++) {
            float xi = x0 + dx;
            if (!(xi >= 0.0f && xi <= 239.0f)) continue;
            float tap = gs1_tap(pl, issem, c, s, (int)yi, (int)xi);
            acc += tap * ((1.0f - fabsf(x - xi)) * wy);
        }
    }
    I2[((size_t)bt*NPL + pc)*MLSQ + idx] = acc;
}

// once: gmax cache from init global map (4x4 max of ch0..5)
__global__ __launch_bounds__(256) void k_gmaxinit(const float* __restrict__ igm,
                                                  float* __restrict__ ws)
{
    int b = blockIdx.z, c = blockIdx.y;
    int idx = blockIdx.x*256 + threadIdx.x;
    int i = idx / ML, j = idx % ML;
    const float* g = igm + ((size_t)b*CHL + c)*MGSQ + (size_t)(4*i)*MG + 4*j;
    float m = -3.0e38f;
    #pragma unroll
    for (int r = 0; r < 4; r++) {
        float4 q = *(const float4*)(g + (size_t)r*MG);
        m = fmaxf(m, fmaxf(fmaxf(q.x, q.y), fmaxf(q.z, q.w)));
    }
    ws[WS_CACHE + ((size_t)b*6 + c)*MLSQ + idx] = m;
}

// per step: fused {done-reset, maxpool, local-map max-merge, disks,
//                  fg window write, mf local channels}
__global__ __launch_bounds__(256) void k_updl(const float* __restrict__ I2,
                                              const float* __restrict__ ws,
                                              const int* __restrict__ dones,
                                              const int* __restrict__ updg,
                                              const int* __restrict__ lmb,
                                              float* __restrict__ fl,
                                              float* __restrict__ fg,
                                              float* __restrict__ out, int t)
{
    int b = blockIdx.y;
    int bt = b*TT + t;
    int idx = blockIdx.x*256 + threadIdx.x;
    int i = idx / ML, j = idx % ML;
    bool done = dones[bt] != 0;
    bool upd  = updg[bt] != 0;
    const float* src = I2 + (size_t)bt*NPL*MLSQ;
    float* lm = fl + (size_t)b*CHL*MLSQ;
    float* mf = out + (size_t)bt*CHMF*MLSQ;

    // 3x3 max pool of plane 0
    float pooled = -3.0e38f;
    for (int di = -1; di <= 1; di++) {
        int ii = i + di; if (ii < 0 || ii >= ML) continue;
        for (int dj = -1; dj <= 1; dj++) {
            int jj = j + dj; if (jj < 0 || jj >= ML) continue;
            pooled = fmaxf(pooled, src[ii*ML + jj]);
        }
    }

    const float* sc = ws + WS_SCAL + bt*8;
    float acx = sc[4], acy = sc[5];
    float ddx = (float)j - acx, ddy = (float)i - acy;
    float d2 = ddx*ddx + ddy*ddy;
    float curr = (d2 <= 4.0f) ? 1.0f : 0.0f;
    float bc   = (d2 <= 1600.0f) ? 1.0f : 0.0f;

    float nv[CHL];
    {
        float o0 = done ? 0.0f : lm[0*MLSQ + idx];
        float o1 = done ? 0.0f : lm[1*MLSQ + idx];
        float o3 = done ? 0.0f : lm[3*MLSQ + idx];
        float o4 = done ? 0.0f : lm[4*MLSQ + idx];
        float o5 = done ? 0.0f : lm[5*MLSQ + idx];
        nv[0] = fmaxf(o0, pooled);
        nv[1] = fmaxf(o1, src[MLSQ + idx]);
        nv[2] = curr;
        nv[3] = fmaxf(o3, curr);
        nv[4] = fmaxf(o4, bc);
        nv[5] = o5;
        #pragma unroll
        for (int k = 0; k < NSEM; k++) {
            float ok = done ? 0.0f : lm[(6+k)*MLSQ + idx];
            nv[6+k] = fmaxf(ok, src[(2+k)*MLSQ + idx]);
        }
    }

    int y0 = lmb[b*4+0], x0 = lmb[b*4+2];
    size_t goff = (size_t)(y0+i)*MG + (x0+j);
    #pragma unroll
    for (int c = 0; c < CHL; c++) {
        lm[c*MLSQ + idx] = nv[c];
        if (upd) fg[((size_t)b*CHL + c)*MGSQ + goff] = nv[c];
    }
    #pragma unroll
    for (int c = 0; c < 6; c++)  mf[c*MLSQ + idx] = nv[c];
    #pragma unroll
    for (int k = 0; k < NSEM; k++) mf[(12+k)*MLSQ + idx] = nv[6+k];
}

// per step: gmax cache update + mf gmax channels (6..11)
__global__ __launch_bounds__(256) void k_gmax(const float* __restrict__ fl,
                                              float* __restrict__ ws,
                                              const int* __restrict__ dones,
                                              const int* __restrict__ updg,
                                              const int* __restrict__ lmb,
                                              float* __restrict__ out, int t)
{
    int b = blockIdx.z, c = blockIdx.y;
    int bt = b*TT + t;
    int idx = blockIdx.x*256 + threadIdx.x;
    int i = idx / ML, j = idx % ML;
    bool done = dones[bt] != 0;
    bool upd  = updg[bt] != 0;
    int y0 = lmb[b*4+0], x0 = lmb[b*4+2];      // window origin (assumed %4==0; holds)
    int iy0 = y0 >> 2, ix0 = x0 >> 2;
    bool inWin = (i >= iy0) && (i < iy0 + ML/4) && (j >= ix0) && (j < ix0 + ML/4);
    float* cache = ws + WS_CACHE + ((size_t)b*6 + c)*MLSQ;
    float v;
    if (inWin && upd) {
        const float* lmc = fl + ((size_t)b*CHL + c)*MLSQ + (size_t)(4*i - y0)*ML + (4*j - x0);
        float m = -3.0e38f;
        #pragma unroll
        for (int r = 0; r < 4; r++) {
            float4 q = *(const float4*)(lmc + (size_t)r*ML);
            m = fmaxf(m, fmaxf(fmaxf(q.x, q.y), fmaxf(q.z, q.w)));
        }
        v = m;
    } else if (done) {
        v = 0.0f;
    } else {
        v = cache[idx];
    }
    cache[idx] = v;
    out[(size_t)bt*CHMF*MLSQ + (6+c)*MLSQ + idx] = v;
}

// after loop: apply deferred done-zeroing of the global map
__global__ __launch_bounds__(256) void k_fgfix(float* __restrict__ fg,
                                               const float* __restrict__ ws,
                                               const int* __restrict__ lmb)
{
    int b = blockIdx.y;
    if (ws[WS_FLAGS + b*2 + 0] < 0.5f) return;       // no done in sequence
    bool zeroWin = ws[WS_FLAGS + b*2 + 1] > 0.5f;
    int y0 = lmb[b*4+0], y1 = lmb[b*4+1], x0 = lmb[b*4+2], x1 = lmb[b*4+3];
    float* p = fg + (size_t)b*CHL*MGSQ;
    for (size_t e = blockIdx.x*256 + threadIdx.x; e < (size_t)CHL*MGSQ;
         e += (size_t)gridDim.x*256) {
        int pix = (int)(e % MGSQ);
        int i = pix / MG, j = pix % MG;
        bool inWin = (i >= y0) && (i < y1) && (j >= x0) && (j < x1);
        if (!inWin || zeroWin) p[e] = 0.0f;
    }
}

extern "C" void kernel_launch(void* const* d_in, const int* in_sizes, int n_in,
                              void* d_out, int out_size, void* d_ws, size_t ws_size,
                              hipStream_t stream)
{
    const float* obs   = (const float*)d_in[0];
    const float* pd    = (const float*)d_in[1];
    const float* cam   = (const float*)d_in[2];
    const float* ilm   = (const float*)d_in[3];
    const float* igm   = (const float*)d_in[4];
    const float* ilp   = (const float*)d_in[5];
    const float* org   = (const float*)d_in[7];
    const int*   dones = (const int*)d_in[8];
    const int*   updg  = (const int*)d_in[9];
    const int*   lmb   = (const int*)d_in[10];
    float* out = (float*)d_out;
    float* ws  = (float*)d_ws;

    float* fl     = out + OFF_FL;
    float* fg     = out + OFF_FG;
    float* planes = ws + WS_PLANES;
    float* I2v    = ws + WS_I2;

    hipMemcpyAsync(fl, ilm, (size_t)SZ_FL*sizeof(float), hipMemcpyDeviceToDevice, stream);
    hipMemcpyAsync(fg, igm, (size_t)SZ_FG*sizeof(float), hipMemcpyDeviceToDevice, stream);
    k_poseall<<<1, 64, 0, stream>>>(pd, ilp, org, lmb, dones, updg, out, ws);
    hipMemsetAsync(planes, 0, (size_t)BB*TT*NPL*VRSQ*sizeof(float), stream);
    k_splat<<<dim3(75, BB*TT), 256, 0, stream>>>(obs, cam, planes);
    k_gs<<<dim3(225, NPL, BB*TT), 256, 0, stream>>>(planes, ws, I2v);
    k_gmaxinit<<<dim3(225, 6, BB), 256, 0, stream>>>(igm, ws);

    for (int t = 0; t < TT; t++) {
        k_updl<<<dim3(225, BB), 256, 0, stream>>>(I2v, ws, dones, updg, lmb, fl, fg, out, t);
        k_gmax<<<dim3(225, 6, BB), 256, 0, stream>>>(fl, ws, dones, updg, lmb, out, t);
    }
    k_fgfix<<<dim3(1024, BB), 256, 0, stream>>>(fg, ws, lmb);
}

// Round 3
// 666.422 us; speedup vs baseline: 1.2232x; 1.1276x over previous
//
#include <hip/hip_runtime.h>
#include <math.h>

#ifndef M_PI
#define M_PI 3.14159265358979323846
#endif

// ---- problem constants ----
#define BB 4
#define TT 4
#define NSEM 16
#define CHL 22            // NC + NUM_SEM
#define CHMF 28           // NC + NC + NUM_SEM
#define ML 240
#define MG 960
#define VR 100
#define HS 120            // FRAME_H/DU
#define WSW 160           // FRAME_W/DU
#define NPL 18            // planes: 0=agent_hp[0], 1=all_hp[0], 2..17=agent_hp[1..16]
#define MLSQ (ML*ML)      // 57600
#define MGSQ (MG*MG)      // 921600
#define VRSQ (VR*VR)      // 10000
#define PPT (HS*WSW)      // 19200 points per (b,t)
#define NPART 12          // row-bands for LDS splat
#define PR 9              // rows per band (12*9=108 >= 100)

// ---- output layout (floats) ----
#define SZ_MF (BB*TT*CHMF*MLSQ)
#define SZ_FL (BB*CHL*MLSQ)
#define SZ_FG (BB*CHL*MGSQ)
#define OFF_FL SZ_MF
#define OFF_FG (OFF_FL + SZ_FL)
#define OFF_LP (OFF_FG + SZ_FG)
#define OFF_GP (OFF_LP + BB*TT*3)
#define OFF_LMB (OFF_GP + BB*TT*3)
#define OFF_ORG (OFF_LMB + BB*TT*4)

// ---- ws layout (floats) ----
#define WS_SCAL 0                                   // (b*TT+t)*8: c,s,stx,sty,acx,acy
#define WS_FLAGS (WS_SCAL + BB*TT*8)                // b*2: anyDone, zeroWin
#define WS_CACHE (WS_FLAGS + 2*BB)                  // B*6*240*240 gmax cache
#define WS_PLANES (WS_CACHE + BB*6*MLSQ)            // B*T*18*100*100
#define WS_I2 (WS_PLANES + BB*TT*NPL*VRSQ)          // B*T*18*240*240
#define PTSN (BB*TT*PPT)
#define WS_GY (WS_I2 + BB*TT*NPL*MLSQ)
#define WS_GX (WS_GY + PTSN)
#define WS_WZA (WS_GX + PTSN)
#define WS_WZL (WS_WZA + PTSN)
#define WS_SEMDS (WS_WZL + PTSN)                    // B*T*16*PPT

// once: all T pose updates (sequential in t, parallel in b) + scalars + flags
__global__ void k_poseall(const float* __restrict__ pd, const float* __restrict__ ilp,
                          const float* __restrict__ org, const int* __restrict__ lmb,
                          const int* __restrict__ dones, const int* __restrict__ updg,
                          float* __restrict__ out, float* __restrict__ ws)
{
    int i = threadIdx.x;
    if (i < BB*TT) {
        int b = i / TT, t = i % TT;
        for (int k = 0; k < 4; k++) out[OFF_LMB + (b*TT+t)*4 + k] = (float)lmb[b*4+k];
        for (int k = 0; k < 3; k++) out[OFF_ORG + (b*TT+t)*3 + k] = org[b*3+k];
    }
    if (i >= BB) return;
    int b = i;
    float p0 = ilp[b*3+0], p1 = ilp[b*3+1], p2 = ilp[b*3+2];
    const float D2R = 0.017453292519943295f;
    int lastDone = -1, lastUpd = -1;
    for (int t = 0; t < TT; t++) {
        if (dones[b*TT+t]) { p0 = 6.0f; p1 = 6.0f; p2 = 0.0f; lastDone = t; }
        if (updg[b*TT+t]) lastUpd = t;
        float tr = p2 * D2R;
        float c0 = cosf(tr), s0 = sinf(tr);
        float q0 = pd[(b*TT+t)*3+0], q1 = pd[(b*TT+t)*3+1], q2 = pd[(b*TT+t)*3+2];
        float nx = p0 + q0*c0 - q1*s0;
        float ny = p1 + q0*s0 + q1*c0;
        float a  = p2 + q2*57.29577951308232f + 180.0f;
        float m  = fmodf(a, 360.0f); if (m < 0.0f) m += 360.0f;
        float nt = m - 180.0f;
        p0 = nx; p1 = ny; p2 = nt;
        out[OFF_LP + (b*TT+t)*3+0] = nx;
        out[OFF_LP + (b*TT+t)*3+1] = ny;
        out[OFF_LP + (b*TT+t)*3+2] = nt;
        out[OFF_GP + (b*TT+t)*3+0] = nx + org[b*3+0];
        out[OFF_GP + (b*TT+t)*3+1] = ny + org[b*3+1];
        out[OFF_GP + (b*TT+t)*3+2] = nt + org[b*3+2];
        float th = (90.0f - nt) * D2R;
        float ax = nx*100.0f/5.0f, ay = ny*100.0f/5.0f;
        float* sc = ws + WS_SCAL + (b*TT+t)*8;
        sc[0] = cosf(th);
        sc[1] = sinf(th);
        sc[2] = -(ax - 120.0f)/120.0f;
        sc[3] = -(ay - 120.0f)/120.0f;
        sc[4] = ax;
        sc[5] = ay;
    }
    ws[WS_FLAGS + b*2 + 0] = (lastDone >= 0) ? 1.0f : 0.0f;
    ws[WS_FLAGS + b*2 + 1] = (lastUpd < lastDone) ? 1.0f : 0.0f;
}

// all (b,t): depth -> point coords + z-collapsed weights + gated sem means
__global__ __launch_bounds__(256) void k_prep(const float* __restrict__ obs,
                                              const float* __restrict__ cam,
                                              float* __restrict__ ws)
{
    int bt = blockIdx.y;
    int b = bt / TT;
    int p = blockIdx.x*256 + threadIdx.x;            // < 19200
    int h = p / WSW, w = p % WSW;
    size_t pi = (size_t)bt*PPT + p;
    const float* ob = obs + (size_t)bt * 20 * 480 * 640;
    float d = ob[(size_t)(3*480 + 4*h)*640 + 4*w];
    if (!(d >= 50.0f && d <= 350.0f)) { ws[WS_GY + pi] = -1000.0f; return; }

    double fd = 640.0 / (2.0 * tan((79.0 * M_PI / 180.0) * 0.5));
    float ff  = (float)fd;
    float xsv = (float)(4*w - 320) / ff;
    float zrv = (240.0f - (float)(4*h)) / ff;
    float elev = atan2f(cam[b*16+9], cam[b*16+10]);
    float ce = cosf(elev), se = sinf(elev);
    float up  = d * zrv;
    float fwd = d*ce + up*se;
    float hgt = -d*se + up*ce + 88.0f;
    float gx = (d*xsv)/5.0f + 50.0f;
    float gy = fwd/5.0f;
    float gz = hgt/5.0f + 8.0f;                      // - ZMIN

    float z0 = floorf(gz);
    float wza = 0.0f, wzl = 0.0f;
    #pragma unroll
    for (int dz = 0; dz < 2; dz++) {
        float zi = z0 + dz;
        float wz = 1.0f - fabsf(gz - zi);
        if (zi >= 0.0f && zi < 80.0f) {
            wzl += wz;
            if (zi >= 13.0f && zi < 25.0f) wza += wz;
        }
    }
    if (wzl == 0.0f && wza == 0.0f) { ws[WS_GY + pi] = -1000.0f; return; }

    ws[WS_GY + pi]  = gy;
    ws[WS_GX + pi]  = gx;
    ws[WS_WZA + pi] = wza;
    ws[WS_WZL + pi] = wzl;

    if (wza > 0.0f) {
        const float* sb = ob + (size_t)4*480*640 + (size_t)(4*h)*640 + 4*w;
        float* so = ws + WS_SEMDS + (size_t)bt*NSEM*PPT + p;
        #pragma unroll
        for (int k = 0; k < NSEM; k++) {
            float s = 0.0f;
            #pragma unroll
            for (int r = 0; r < 4; r++) {
                const float4 v = *(const float4*)(sb + (size_t)k*480*640 + r*640);
                s += v.x + v.y + v.z + v.w;
            }
            so[(size_t)k*PPT] = s * 0.0625f;
        }
    }
}

// one block per (bt, row-band): LDS-accumulated bilinear splat, plain-store flush
__global__ __launch_bounds__(256) void k_splat2(const float* __restrict__ ws,
                                                float* __restrict__ planes)
{
    int bt = blockIdx.x;
    int part = blockIdx.y;
    int rlo = part * PR;
    __shared__ float acc[NPL*PR*VR];                 // 64800 B
    for (int e = threadIdx.x; e < NPL*PR*VR; e += 256) acc[e] = 0.0f;
    __syncthreads();

    const float* gyA  = ws + WS_GY  + (size_t)bt*PPT;
    const float* gxA  = ws + WS_GX  + (size_t)bt*PPT;
    const float* wzaA = ws + WS_WZA + (size_t)bt*PPT;
    const float* wzlA = ws + WS_WZL + (size_t)bt*PPT;
    const float* semA = ws + WS_SEMDS + (size_t)bt*NSEM*PPT;

    for (int p = threadIdx.x; p < PPT; p += 256) {
        float gy = gyA[p];
        float y0 = floorf(gy);
        if (y0 > (float)(rlo + PR - 1) || y0 + 1.0f < (float)rlo) continue;
        float gx  = gxA[p];
        float wza = wzaA[p];
        float wzl = wzlA[p];
        float x0 = floorf(gx);
        float sem[NSEM];
        if (wza > 0.0f) {
            #pragma unroll
            for (int k = 0; k < NSEM; k++) sem[k] = semA[(size_t)k*PPT + p];
        }
        #pragma unroll
        for (int dy = 0; dy < 2; dy++) {
            float yi = y0 + dy;
            if (!(yi >= 0.0f && yi < 100.0f)) continue;
            int r = (int)yi - rlo;
            if (r < 0 || r >= PR) continue;
            float wy = 1.0f - fabsf(gy - yi);
            #pragma unroll
            for (int dx = 0; dx < 2; dx++) {
                float xi = x0 + dx;
                if (!(xi >= 0.0f && xi < 100.0f)) continue;
                float wxy = (1.0f - fabsf(gx - xi)) * wy;
                if (wxy <= 0.0f) continue;
                int cell = r*VR + (int)xi;
                if (wza > 0.0f) {
                    atomicAdd(&acc[cell], wza*wxy);
                    #pragma unroll
                    for (int k = 0; k < NSEM; k++) {
                        float sv = sem[k];
                        if (sv != 0.0f) atomicAdd(&acc[(2+k)*PR*VR + cell], sv*wza*wxy);
                    }
                }
                if (wzl > 0.0f) atomicAdd(&acc[PR*VR + cell], wzl*wxy);
            }
        }
    }
    __syncthreads();

    int nrows = 100 - rlo; if (nrows > PR) nrows = PR;
    if (nrows <= 0) return;
    float* pl = planes + (size_t)bt*NPL*VRSQ;
    for (int e = threadIdx.x; e < NPL*nrows*VR; e += 256) {
        int c = e / (nrows*VR);
        int rc = e % (nrows*VR);
        int r = rc / VR, x = rc % VR;
        pl[(size_t)c*VRSQ + (rlo + r)*VR + x] = acc[c*PR*VR + r*VR + x];
    }
}

// gs1 value at integer I1 pixel (ii,jj) — identical arithmetic to 2-pass version
__device__ __forceinline__ float gs1_tap(const float* __restrict__ pl, bool issem,
                                         float c, float s, int ii, int jj)
{
    float xg = (float)jj * (float)(2.0/239.0) - 1.0f;
    float yg = (float)ii * (float)(2.0/239.0) - 1.0f;
    float gxr = c*xg - s*yg;
    float gyr = s*xg + c*yg;
    float x = (gxr + 1.0f)*0.5f*239.0f;
    float y = (gyr + 1.0f)*0.5f*239.0f;
    float x0 = floorf(x), y0 = floorf(y);
    float acc = 0.0f;
    #pragma unroll
    for (int dy = 0; dy < 2; dy++) {
        float yi = y0 + dy;
        if (!(yi >= 120.0f && yi < 220.0f)) continue;
        float wy = 1.0f - fabsf(y - yi);
        #pragma unroll
        for (int dx = 0; dx < 2; dx++) {
            float xi = x0 + dx;
            if (!(xi >= 70.0f && xi < 170.0f)) continue;
            float v = pl[((int)yi - 120)*VR + ((int)xi - 70)];
            if (issem) v = v / 5.0f;
            v = fminf(v, 1.0f);
            acc += v * ((1.0f - fabsf(x - xi)) * wy);
        }
    }
    return acc;
}

// fused gs1∘gs2 for all (b,t): writes I2 directly (recomputes the 4 I1 taps)
__global__ __launch_bounds__(256) void k_gs(const float* __restrict__ planes,
                                            const float* __restrict__ ws,
                                            float* __restrict__ I2)
{
    int bt = blockIdx.z, pc = blockIdx.y;
    int idx = blockIdx.x*256 + threadIdx.x;
    int i = idx / ML, j = idx % ML;
    const float* sc = ws + WS_SCAL + bt*8;
    float c = sc[0], s = sc[1], stx = sc[2], sty = sc[3];
    float xg = (float)j * (float)(2.0/239.0) - 1.0f + stx;
    float yg = (float)i * (float)(2.0/239.0) - 1.0f + sty;
    float x = (xg + 1.0f)*0.5f*239.0f;
    float y = (yg + 1.0f)*0.5f*239.0f;
    float x0 = floorf(x), y0 = floorf(y);
    const float* pl = planes + ((size_t)bt*NPL + pc)*VRSQ;
    bool issem = (pc >= 2);
    float acc = 0.0f;
    #pragma unroll
    for (int dy = 0; dy < 2; dy++) {
        float yi = y0 + dy;
        if (!(yi >= 0.0f && yi <= 239.0f)) continue;
        float wy = 1.0f - fabsf(y - yi);
        #pragma unroll
        for (int dx = 0; dx < 2; dx++) {
            float xi = x0 + dx;
            if (!(xi >= 0.0f && xi <= 239.0f)) continue;
            float tap = gs1_tap(pl, issem, c, s, (int)yi, (int)xi);
            acc += tap * ((1.0f - fabsf(x - xi)) * wy);
        }
    }
    I2[((size_t)bt*NPL + pc)*MLSQ + idx] = acc;
}

// once: gmax cache from init global map (4x4 max of ch0..5)
__global__ __launch_bounds__(256) void k_gmaxinit(const float* __restrict__ igm,
                                                  float* __restrict__ ws)
{
    int b = blockIdx.z, c = blockIdx.y;
    int idx = blockIdx.x*256 + threadIdx.x;
    int i = idx / ML, j = idx % ML;
    const float* g = igm + ((size_t)b*CHL + c)*MGSQ + (size_t)(4*i)*MG + 4*j;
    float m = -3.0e38f;
    #pragma unroll
    for (int r = 0; r < 4; r++) {
        float4 q = *(const float4*)(g + (size_t)r*MG);
        m = fmaxf(m, fmaxf(fmaxf(q.x, q.y), fmaxf(q.z, q.w)));
    }
    ws[WS_CACHE + ((size_t)b*6 + c)*MLSQ + idx] = m;
}

// per step: fused {done-reset, maxpool, local-map max-merge, disks,
//                  fg window write, mf local channels}
__global__ __launch_bounds__(256) void k_updl(const float* __restrict__ I2,
                                              const float* __restrict__ ws,
                                              const int* __restrict__ dones,
                                              const int* __restrict__ updg,
                                              const int* __restrict__ lmb,
                                              float* __restrict__ fl,
                                              float* __restrict__ fg,
                                              float* __restrict__ out, int t)
{
    int b = blockIdx.y;
    int bt = b*TT + t;
    int idx = blockIdx.x*256 + threadIdx.x;
    int i = idx / ML, j = idx % ML;
    bool done = dones[bt] != 0;
    bool upd  = updg[bt] != 0;
    const float* src = I2 + (size_t)bt*NPL*MLSQ;
    float* lm = fl + (size_t)b*CHL*MLSQ;
    float* mf = out + (size_t)bt*CHMF*MLSQ;

    // 3x3 max pool of plane 0
    float pooled = -3.0e38f;
    for (int di = -1; di <= 1; di++) {
        int ii = i + di; if (ii < 0 || ii >= ML) continue;
        for (int dj = -1; dj <= 1; dj++) {
            int jj = j + dj; if (jj < 0 || jj >= ML) continue;
            pooled = fmaxf(pooled, src[ii*ML + jj]);
        }
    }

    const float* sc = ws + WS_SCAL + bt*8;
    float acx = sc[4], acy = sc[5];
    float ddx = (float)j - acx, ddy = (float)i - acy;
    float d2 = ddx*ddx + ddy*ddy;
    float curr = (d2 <= 4.0f) ? 1.0f : 0.0f;
    float bc   = (d2 <= 1600.0f) ? 1.0f : 0.0f;

    float nv[CHL];
    {
        float o0 = done ? 0.0f : lm[0*MLSQ + idx];
        float o1 = done ? 0.0f : lm[1*MLSQ + idx];
        float o3 = done ? 0.0f : lm[3*MLSQ + idx];
        float o4 = done ? 0.0f : lm[4*MLSQ + idx];
        float o5 = done ? 0.0f : lm[5*MLSQ + idx];
        nv[0] = fmaxf(o0, pooled);
        nv[1] = fmaxf(o1, src[MLSQ + idx]);
        nv[2] = curr;
        nv[3] = fmaxf(o3, curr);
        nv[4] = fmaxf(o4, bc);
        nv[5] = o5;
        #pragma unroll
        for (int k = 0; k < NSEM; k++) {
            float ok = done ? 0.0f : lm[(6+k)*MLSQ + idx];
            nv[6+k] = fmaxf(ok, src[(2+k)*MLSQ + idx]);
        }
    }

    int y0 = lmb[b*4+0], x0 = lmb[b*4+2];
    size_t goff = (size_t)(y0+i)*MG + (x0+j);
    #pragma unroll
    for (int c = 0; c < CHL; c++) {
        lm[c*MLSQ + idx] = nv[c];
        if (upd) fg[((size_t)b*CHL + c)*MGSQ + goff] = nv[c];
    }
    #pragma unroll
    for (int c = 0; c < 6; c++)  mf[c*MLSQ + idx] = nv[c];
    #pragma unroll
    for (int k = 0; k < NSEM; k++) mf[(12+k)*MLSQ + idx] = nv[6+k];
}

// per step: gmax cache update + mf gmax channels (6..11)
__global__ __launch_bounds__(256) void k_gmax(const float* __restrict__ fl,
                                              float* __restrict__ ws,
                                              const int* __restrict__ dones,
                                              const int* __restrict__ updg,
                                              const int* __restrict__ lmb,
                                              float* __restrict__ out, int t)
{
    int b = blockIdx.z, c = blockIdx.y;
    int bt = b*TT + t;
    int idx = blockIdx.x*256 + threadIdx.x;
    int i = idx / ML, j = idx % ML;
    bool done = dones[bt] != 0;
    bool upd  = updg[bt] != 0;
    int y0 = lmb[b*4+0], x0 = lmb[b*4+2];      // window origin (%4==0 holds)
    int iy0 = y0 >> 2, ix0 = x0 >> 2;
    bool inWin = (i >= iy0) && (i < iy0 + ML/4) && (j >= ix0) && (j < ix0 + ML/4);
    float* cache = ws + WS_CACHE + ((size_t)b*6 + c)*MLSQ;
    float v;
    if (inWin && upd) {
        const float* lmc = fl + ((size_t)b*CHL + c)*MLSQ + (size_t)(4*i - y0)*ML + (4*j - x0);
        float m = -3.0e38f;
        #pragma unroll
        for (int r = 0; r < 4; r++) {
            float4 q = *(const float4*)(lmc + (size_t)r*ML);
            m = fmaxf(m, fmaxf(fmaxf(q.x, q.y), fmaxf(q.z, q.w)));
        }
        v = m;
    } else if (done) {
        v = 0.0f;
    } else {
        v = cache[idx];
    }
    cache[idx] = v;
    out[(size_t)bt*CHMF*MLSQ + (6+c)*MLSQ + idx] = v;
}

// after loop: apply deferred done-zeroing of the global map
__global__ __launch_bounds__(256) void k_fgfix(float* __restrict__ fg,
                                               const float* __restrict__ ws,
                                               const int* __restrict__ lmb)
{
    int b = blockIdx.y;
    if (ws[WS_FLAGS + b*2 + 0] < 0.5f) return;       // no done in sequence
    bool zeroWin = ws[WS_FLAGS + b*2 + 1] > 0.5f;
    int y0 = lmb[b*4+0], y1 = lmb[b*4+1], x0 = lmb[b*4+2], x1 = lmb[b*4+3];
    float* p = fg + (size_t)b*CHL*MGSQ;
    for (size_t e = blockIdx.x*256 + threadIdx.x; e < (size_t)CHL*MGSQ;
         e += (size_t)gridDim.x*256) {
        int pix = (int)(e % MGSQ);
        int i = pix / MG, j = pix % MG;
        bool inWin = (i >= y0) && (i < y1) && (j >= x0) && (j < x1);
        if (!inWin || zeroWin) p[e] = 0.0f;
    }
}

extern "C" void kernel_launch(void* const* d_in, const int* in_sizes, int n_in,
                              void* d_out, int out_size, void* d_ws, size_t ws_size,
                              hipStream_t stream)
{
    const float* obs   = (const float*)d_in[0];
    const float* pd    = (const float*)d_in[1];
    const float* cam   = (const float*)d_in[2];
    const float* ilm   = (const float*)d_in[3];
    const float* igm   = (const float*)d_in[4];
    const float* ilp   = (const float*)d_in[5];
    const float* org   = (const float*)d_in[7];
    const int*   dones = (const int*)d_in[8];
    const int*   updg  = (const int*)d_in[9];
    const int*   lmb   = (const int*)d_in[10];
    float* out = (float*)d_out;
    float* ws  = (float*)d_ws;

    float* fl     = out + OFF_FL;
    float* fg     = out + OFF_FG;
    float* planes = ws + WS_PLANES;
    float* I2v    = ws + WS_I2;

    hipMemcpyAsync(fl, ilm, (size_t)SZ_FL*sizeof(float), hipMemcpyDeviceToDevice, stream);
    hipMemcpyAsync(fg, igm, (size_t)SZ_FG*sizeof(float), hipMemcpyDeviceToDevice, stream);
    k_poseall<<<1, 64, 0, stream>>>(pd, ilp, org, lmb, dones, updg, out, ws);
    k_prep<<<dim3(75, BB*TT), 256, 0, stream>>>(obs, cam, ws);
    k_splat2<<<dim3(BB*TT, NPART), 256, 0, stream>>>(ws, planes);
    k_gs<<<dim3(225, NPL, BB*TT), 256, 0, stream>>>(planes, ws, I2v);
    k_gmaxinit<<<dim3(225, 6, BB), 256, 0, stream>>>(igm, ws);

    for (int t = 0; t < TT; t++) {
        k_updl<<<dim3(225, BB), 256, 0, stream>>>(I2v, ws, dones, updg, lmb, fl, fg, out, t);
        k_gmax<<<dim3(225, 6, BB), 256, 0, stream>>>(fl, ws, dones, updg, lmb, out, t);
    }
    k_fgfix<<<dim3(1024, BB), 256, 0, stream>>>(fg, ws, lmb);
}

// Round 4
// 503.416 us; speedup vs baseline: 1.6193x; 1.3238x over previous
//
#include <hip/hip_runtime.h>
#include <math.h>

#ifndef M_PI
#define M_PI 3.14159265358979323846
#endif

// ---- problem constants ----
#define BB 4
#define TT 4
#define NSEM 16
#define CHL 22            // NC + NUM_SEM
#define CHMF 28           // NC + NC + NUM_SEM
#define ML 240
#define MG 960
#define VR 100
#define HS 120            // FRAME_H/DU
#define WSW 160           // FRAME_W/DU
#define NPL 18            // planes: 0=agent_hp[0], 1=all_hp[0], 2..17=agent_hp[1..16]
#define MLSQ (ML*ML)      // 57600
#define MGSQ (MG*MG)      // 921600
#define VRSQ (VR*VR)      // 10000
#define PPT (HS*WSW)      // 19200 points per (b,t)
#define NPART 12          // row-bands for LDS splat
#define PR 9              // rows per band (12*9=108 >= 100)
#define NGRP 5            // channel groups: {0,1},{2-5},{6-9},{10-13},{14-17}

// ---- output layout (floats) ----
#define SZ_MF (BB*TT*CHMF*MLSQ)
#define SZ_FL (BB*CHL*MLSQ)
#define SZ_FG (BB*CHL*MGSQ)
#define OFF_FL SZ_MF
#define OFF_FG (OFF_FL + SZ_FL)
#define OFF_LP (OFF_FG + SZ_FG)
#define OFF_GP (OFF_LP + BB*TT*3)
#define OFF_LMB (OFF_GP + BB*TT*3)
#define OFF_ORG (OFF_LMB + BB*TT*4)

// ---- ws layout (floats) ----
#define WS_SCAL 0                                   // (b*TT+t)*8: c,s,stx,sty,acx,acy
#define WS_FLAGS (WS_SCAL + BB*TT*8)                // b*4: anyDone, zeroWin, lastUpd, pad
#define WS_CACHE (WS_FLAGS + 4*BB)                  // B*6*240*240 init gmax cache
#define WS_PLANES (WS_CACHE + BB*6*MLSQ)            // B*T*18*100*100
#define WS_I2 (WS_PLANES + BB*TT*NPL*VRSQ)          // B*T*18*240*240
#define PTSN (BB*TT*PPT)
#define WS_GY (WS_I2 + BB*TT*NPL*MLSQ)
#define WS_GX (WS_GY + PTSN)
#define WS_WZA (WS_GX + PTSN)
#define WS_WZL (WS_WZA + PTSN)
#define WS_SEMDS (WS_WZL + PTSN)                    // B*T*16*PPT

// once: all T pose updates (sequential in t, parallel in b) + scalars + flags
__global__ void k_poseall(const float* __restrict__ pd, const float* __restrict__ ilp,
                          const float* __restrict__ org, const int* __restrict__ lmb,
                          const int* __restrict__ dones, const int* __restrict__ updg,
                          float* __restrict__ out, float* __restrict__ ws)
{
    int i = threadIdx.x;
    if (i < BB*TT) {
        int b = i / TT, t = i % TT;
        for (int k = 0; k < 4; k++) out[OFF_LMB + (b*TT+t)*4 + k] = (float)lmb[b*4+k];
        for (int k = 0; k < 3; k++) out[OFF_ORG + (b*TT+t)*3 + k] = org[b*3+k];
    }
    if (i >= BB) return;
    int b = i;
    float p0 = ilp[b*3+0], p1 = ilp[b*3+1], p2 = ilp[b*3+2];
    const float D2R = 0.017453292519943295f;
    int lastDone = -1, lastUpd = -1;
    for (int t = 0; t < TT; t++) {
        if (dones[b*TT+t]) { p0 = 6.0f; p1 = 6.0f; p2 = 0.0f; lastDone = t; }
        if (updg[b*TT+t]) lastUpd = t;
        float tr = p2 * D2R;
        float c0 = cosf(tr), s0 = sinf(tr);
        float q0 = pd[(b*TT+t)*3+0], q1 = pd[(b*TT+t)*3+1], q2 = pd[(b*TT+t)*3+2];
        float nx = p0 + q0*c0 - q1*s0;
        float ny = p1 + q0*s0 + q1*c0;
        float a  = p2 + q2*57.29577951308232f + 180.0f;
        float m  = fmodf(a, 360.0f); if (m < 0.0f) m += 360.0f;
        float nt = m - 180.0f;
        p0 = nx; p1 = ny; p2 = nt;
        out[OFF_LP + (b*TT+t)*3+0] = nx;
        out[OFF_LP + (b*TT+t)*3+1] = ny;
        out[OFF_LP + (b*TT+t)*3+2] = nt;
        out[OFF_GP + (b*TT+t)*3+0] = nx + org[b*3+0];
        out[OFF_GP + (b*TT+t)*3+1] = ny + org[b*3+1];
        out[OFF_GP + (b*TT+t)*3+2] = nt + org[b*3+2];
        float th = (90.0f - nt) * D2R;
        float ax = nx*100.0f/5.0f, ay = ny*100.0f/5.0f;
        float* sc = ws + WS_SCAL + (b*TT+t)*8;
        sc[0] = cosf(th);
        sc[1] = sinf(th);
        sc[2] = -(ax - 120.0f)/120.0f;
        sc[3] = -(ay - 120.0f)/120.0f;
        sc[4] = ax;
        sc[5] = ay;
    }
    ws[WS_FLAGS + b*4 + 0] = (lastDone >= 0) ? 1.0f : 0.0f;
    ws[WS_FLAGS + b*4 + 1] = (lastUpd < lastDone) ? 1.0f : 0.0f;
    ws[WS_FLAGS + b*4 + 2] = (float)lastUpd;
}

// all (b,t): depth -> point coords + z-collapsed weights + gated sem means
__global__ __launch_bounds__(256) void k_prep(const float* __restrict__ obs,
                                              const float* __restrict__ cam,
                                              float* __restrict__ ws)
{
    int bt = blockIdx.y;
    int b = bt / TT;
    int p = blockIdx.x*256 + threadIdx.x;            // < 19200
    int h = p / WSW, w = p % WSW;
    size_t pi = (size_t)bt*PPT + p;
    const float* ob = obs + (size_t)bt * 20 * 480 * 640;
    float d = ob[(size_t)(3*480 + 4*h)*640 + 4*w];
    if (!(d >= 50.0f && d <= 350.0f)) { ws[WS_GY + pi] = -1000.0f; return; }

    double fd = 640.0 / (2.0 * tan((79.0 * M_PI / 180.0) * 0.5));
    float ff  = (float)fd;
    float xsv = (float)(4*w - 320) / ff;
    float zrv = (240.0f - (float)(4*h)) / ff;
    float elev = atan2f(cam[b*16+9], cam[b*16+10]);
    float ce = cosf(elev), se = sinf(elev);
    float up  = d * zrv;
    float fwd = d*ce + up*se;
    float hgt = -d*se + up*ce + 88.0f;
    float gx = (d*xsv)/5.0f + 50.0f;
    float gy = fwd/5.0f;
    float gz = hgt/5.0f + 8.0f;                      // - ZMIN

    float z0 = floorf(gz);
    float wza = 0.0f, wzl = 0.0f;
    #pragma unroll
    for (int dz = 0; dz < 2; dz++) {
        float zi = z0 + dz;
        float wz = 1.0f - fabsf(gz - zi);
        if (zi >= 0.0f && zi < 80.0f) {
            wzl += wz;
            if (zi >= 13.0f && zi < 25.0f) wza += wz;
        }
    }
    if (wzl == 0.0f && wza == 0.0f) { ws[WS_GY + pi] = -1000.0f; return; }

    ws[WS_GY + pi]  = gy;
    ws[WS_GX + pi]  = gx;
    ws[WS_WZA + pi] = wza;
    ws[WS_WZL + pi] = wzl;

    if (wza > 0.0f) {
        const float* sb = ob + (size_t)4*480*640 + (size_t)(4*h)*640 + 4*w;
        float* so = ws + WS_SEMDS + (size_t)bt*NSEM*PPT + p;
        #pragma unroll
        for (int k = 0; k < NSEM; k++) {
            float s = 0.0f;
            #pragma unroll
            for (int r = 0; r < 4; r++) {
                const float4 v = *(const float4*)(sb + (size_t)k*480*640 + r*640);
                s += v.x + v.y + v.z + v.w;
            }
            so[(size_t)k*PPT] = s * 0.0625f;
        }
    }
}

// one block per (bt, row-band, ch-group): LDS-accumulated bilinear splat
__global__ __launch_bounds__(256) void k_splat2(const float* __restrict__ ws,
                                                float* __restrict__ planes)
{
    int bt = blockIdx.x;
    int part = blockIdx.y;
    int grp = blockIdx.z;
    int rlo = part * PR;
    int c0  = (grp == 0) ? 0 : (2 + 4*(grp-1));
    int nch = (grp == 0) ? 2 : 4;
    __shared__ float acc[4*PR*VR];                   // 14.4 KB max
    for (int e = threadIdx.x; e < nch*PR*VR; e += 256) acc[e] = 0.0f;
    __syncthreads();

    const float* gyA  = ws + WS_GY  + (size_t)bt*PPT;
    const float* gxA  = ws + WS_GX  + (size_t)bt*PPT;
    const float* wzaA = ws + WS_WZA + (size_t)bt*PPT;
    const float* wzlA = ws + WS_WZL + (size_t)bt*PPT;
    const float* semA = ws + WS_SEMDS + (size_t)bt*NSEM*PPT + (size_t)(c0-2)*PPT;

    for (int p = threadIdx.x; p < PPT; p += 256) {
        float gy = gyA[p];
        float y0 = floorf(gy);
        if (y0 > (float)(rlo + PR - 1) || y0 + 1.0f < (float)rlo) continue;
        float wza = wzaA[p];
        if (grp != 0 && wza <= 0.0f) continue;
        float gx  = gxA[p];
        float x0 = floorf(gx);
        float sem[4];
        if (grp != 0) {
            #pragma unroll
            for (int k = 0; k < 4; k++) sem[k] = semA[(size_t)k*PPT + p];
        }
        float wzl = (grp == 0) ? wzlA[p] : 0.0f;
        #pragma unroll
        for (int dy = 0; dy < 2; dy++) {
            float yi = y0 + dy;
            if (!(yi >= 0.0f && yi < 100.0f)) continue;
            int r = (int)yi - rlo;
            if (r < 0 || r >= PR) continue;
            float wy = 1.0f - fabsf(gy - yi);
            #pragma unroll
            for (int dx = 0; dx < 2; dx++) {
                float xi = x0 + dx;
                if (!(xi >= 0.0f && xi < 100.0f)) continue;
                float wxy = (1.0f - fabsf(gx - xi)) * wy;
                if (wxy <= 0.0f) continue;
                int cell = r*VR + (int)xi;
                if (grp == 0) {
                    if (wza > 0.0f) atomicAdd(&acc[cell], wza*wxy);
                    if (wzl > 0.0f) atomicAdd(&acc[PR*VR + cell], wzl*wxy);
                } else {
                    #pragma unroll
                    for (int k = 0; k < 4; k++) {
                        float sv = sem[k];
                        if (sv != 0.0f) atomicAdd(&acc[k*PR*VR + cell], sv*wza*wxy);
                    }
                }
            }
        }
    }
    __syncthreads();

    int nrows = 100 - rlo; if (nrows > PR) nrows = PR;
    if (nrows <= 0) return;
    float* pl = planes + (size_t)bt*NPL*VRSQ;
    for (int e = threadIdx.x; e < nch*nrows*VR; e += 256) {
        int c = e / (nrows*VR);
        int rc = e % (nrows*VR);
        int r = rc / VR, x = rc % VR;
        pl[(size_t)(c0+c)*VRSQ + (rlo + r)*VR + x] = acc[c*PR*VR + r*VR + x];
    }
}

// gs1 value at integer I1 pixel (ii,jj) — identical arithmetic to 2-pass version
__device__ __forceinline__ float gs1_tap(const float* __restrict__ pl, bool issem,
                                         float c, float s, int ii, int jj)
{
    float xg = (float)jj * (float)(2.0/239.0) - 1.0f;
    float yg = (float)ii * (float)(2.0/239.0) - 1.0f;
    float gxr = c*xg - s*yg;
    float gyr = s*xg + c*yg;
    float x = (gxr + 1.0f)*0.5f*239.0f;
    float y = (gyr + 1.0f)*0.5f*239.0f;
    float x0 = floorf(x), y0 = floorf(y);
    float acc = 0.0f;
    #pragma unroll
    for (int dy = 0; dy < 2; dy++) {
        float yi = y0 + dy;
        if (!(yi >= 120.0f && yi < 220.0f)) continue;
        float wy = 1.0f - fabsf(y - yi);
        #pragma unroll
        for (int dx = 0; dx < 2; dx++) {
            float xi = x0 + dx;
            if (!(xi >= 70.0f && xi < 170.0f)) continue;
            float v = pl[((int)yi - 120)*VR + ((int)xi - 70)];
            if (issem) v = v / 5.0f;
            v = fminf(v, 1.0f);
            acc += v * ((1.0f - fabsf(x - xi)) * wy);
        }
    }
    return acc;
}

// fused gs1∘gs2 for all (b,t): writes I2 directly (recomputes the 4 I1 taps)
__global__ __launch_bounds__(256) void k_gs(const float* __restrict__ planes,
                                            const float* __restrict__ ws,
                                            float* __restrict__ I2)
{
    int bt = blockIdx.z, pc = blockIdx.y;
    int idx = blockIdx.x*256 + threadIdx.x;
    int i = idx / ML, j = idx % ML;
    const float* sc = ws + WS_SCAL + bt*8;
    float c = sc[0], s = sc[1], stx = sc[2], sty = sc[3];
    float xg = (float)j * (float)(2.0/239.0) - 1.0f + stx;
    float yg = (float)i * (float)(2.0/239.0) - 1.0f + sty;
    float x = (xg + 1.0f)*0.5f*239.0f;
    float y = (yg + 1.0f)*0.5f*239.0f;
    float x0 = floorf(x), y0 = floorf(y);
    const float* pl = planes + ((size_t)bt*NPL + pc)*VRSQ;
    bool issem = (pc >= 2);
    float acc = 0.0f;
    #pragma unroll
    for (int dy = 0; dy < 2; dy++) {
        float yi = y0 + dy;
        if (!(yi >= 0.0f && yi <= 239.0f)) continue;
        float wy = 1.0f - fabsf(y - yi);
        #pragma unroll
        for (int dx = 0; dx < 2; dx++) {
            float xi = x0 + dx;
            if (!(xi >= 0.0f && xi <= 239.0f)) continue;
            float tap = gs1_tap(pl, issem, c, s, (int)yi, (int)xi);
            acc += tap * ((1.0f - fabsf(x - xi)) * wy);
        }
    }
    I2[((size_t)bt*NPL + pc)*MLSQ + idx] = acc;
}

// once: gmax init cache from igm ch0..5 + fg copy of those channels
__global__ __launch_bounds__(256) void k_gmaxinit2(const float* __restrict__ igm,
                                                   float* __restrict__ fg,
                                                   float* __restrict__ ws)
{
    int b = blockIdx.z, c = blockIdx.y;
    int idx = blockIdx.x*256 + threadIdx.x;
    int i = idx / ML, j = idx % ML;
    size_t base = ((size_t)b*CHL + c)*MGSQ + (size_t)(4*i)*MG + 4*j;
    const float* g = igm + base;
    float* go = fg + base;
    float m = -3.0e38f;
    #pragma unroll
    for (int r = 0; r < 4; r++) {
        float4 q = *(const float4*)(g + (size_t)r*MG);
        *(float4*)(go + (size_t)r*MG) = q;
        m = fmaxf(m, fmaxf(fmaxf(q.x, q.y), fmaxf(q.z, q.w)));
    }
    ws[WS_CACHE + ((size_t)b*6 + c)*MLSQ + idx] = m;
}

// once: fg copy of channels 6..21 (grid-stride float4)
__global__ __launch_bounds__(256) void k_copy16(const float* __restrict__ igm,
                                                float* __restrict__ fg)
{
    const size_t per_b = (size_t)16*MGSQ;            // floats
    const size_t N = (size_t)BB*per_b/4;             // float4 count
    for (size_t e = (size_t)blockIdx.x*256 + threadIdx.x; e < N;
         e += (size_t)gridDim.x*256) {
        size_t f = e*4;
        int b = (int)(f / per_b);
        size_t rem = f - (size_t)b*per_b;
        size_t off = ((size_t)b*CHL + 6)*MGSQ + rem;
        *(float4*)(fg+off) = *(const float4*)(igm+off);
    }
}

// mega-kernel: all 4 steps in registers. block = 64 cols x 4 rows.
// Writes: per-t mf local ch(0-5,12-27), per-t in-window gmax (mf ch6-11),
//         final fl, fg window at t==lastUpd.
__global__ __launch_bounds__(256) void k_updl_all(const float* __restrict__ I2,
                                                  const float* __restrict__ ws,
                                                  const float* __restrict__ ilm,
                                                  const int* __restrict__ dones,
                                                  const int* __restrict__ updg,
                                                  const int* __restrict__ lmb,
                                                  float* __restrict__ fl,
                                                  float* __restrict__ fg,
                                                  float* __restrict__ out)
{
    int b  = blockIdx.z;
    int gi = blockIdx.y;                             // 0..59 (4-row group)
    int bx = blockIdx.x;                             // 0..3 col tile
    int lane = threadIdx.x & 63, wv = threadIdx.x >> 6;
    int j0 = (bx < 3) ? bx*64 : 176;                 // tile 3 overlaps tile 2 (benign)
    int j = j0 + lane;
    int i = gi*4 + wv;
    int idx = i*ML + j;

    __shared__ float red[4][6][16];

    const float* lmsrc = ilm + (size_t)b*CHL*MLSQ;
    float* lm = fl + (size_t)b*CHL*MLSQ;
    int y0 = lmb[b*4+0], x0 = lmb[b*4+2];            // %4==0 holds for this problem
    int lastUpd = (int)ws[WS_FLAGS + b*4 + 2];

    float S[CHL];
    #pragma unroll
    for (int c = 0; c < CHL; c++) S[c] = (c == 2) ? 0.0f : lmsrc[c*MLSQ + idx];

    bool writer = (wv == 0) && ((lane & 3) == 0);
    int cx = lane >> 2;
    int cellY = (y0 >> 2) + gi;
    int cellX = (x0 >> 2) + (j0 >> 2) + cx;
    float W[6];
    if (writer) {
        #pragma unroll
        for (int c = 0; c < 6; c++)
            W[c] = ws[WS_CACHE + ((size_t)b*6 + c)*MLSQ + cellY*ML + cellX];
    }

    for (int t = 0; t < TT; t++) {
        int bt = b*TT + t;
        bool done = dones[bt] != 0;
        bool upd  = updg[bt] != 0;
        if (done) {
            #pragma unroll
            for (int c = 0; c < CHL; c++) S[c] = 0.0f;
        }
        const float* src = I2 + (size_t)bt*NPL*MLSQ;

        float pooled = -3.0e38f;
        for (int di = -1; di <= 1; di++) {
            int ii = i + di; if (ii < 0 || ii >= ML) continue;
            for (int dj = -1; dj <= 1; dj++) {
                int jj = j + dj; if (jj < 0 || jj >= ML) continue;
                pooled = fmaxf(pooled, src[ii*ML + jj]);
            }
        }
        const float* sc = ws + WS_SCAL + bt*8;
        float acx = sc[4], acy = sc[5];
        float ddx = (float)j - acx, ddy = (float)i - acy;
        float d2 = ddx*ddx + ddy*ddy;
        float curr = (d2 <= 4.0f) ? 1.0f : 0.0f;
        float bc   = (d2 <= 1600.0f) ? 1.0f : 0.0f;

        S[0] = fmaxf(S[0], pooled);
        S[1] = fmaxf(S[1], src[MLSQ + idx]);
        S[2] = curr;
        S[3] = fmaxf(S[3], curr);
        S[4] = fmaxf(S[4], bc);
        #pragma unroll
        for (int k = 0; k < NSEM; k++)
            S[6+k] = fmaxf(S[6+k], src[(2+k)*MLSQ + idx]);

        float* mf = out + (size_t)bt*CHMF*MLSQ;
        #pragma unroll
        for (int c = 0; c < 6; c++)  mf[c*MLSQ + idx] = S[c];
        #pragma unroll
        for (int k = 0; k < NSEM; k++) mf[(12+k)*MLSQ + idx] = S[6+k];

        if (t == lastUpd) {
            size_t goff = (size_t)(y0+i)*MG + (x0+j);
            #pragma unroll
            for (int c = 0; c < CHL; c++)
                fg[((size_t)b*CHL + c)*MGSQ + goff] = S[c];
        }

        // in-window gmax: 4-col shfl reduce + cross-wave LDS reduce
        #pragma unroll
        for (int c = 0; c < 6; c++) {
            float v = S[c];
            v = fmaxf(v, __shfl_xor(v, 1, 64));
            v = fmaxf(v, __shfl_xor(v, 2, 64));
            if ((lane & 3) == 0) red[wv][c][cx] = v;
        }
        __syncthreads();
        if (writer) {
            #pragma unroll
            for (int c = 0; c < 6; c++) {
                if (done) W[c] = 0.0f;
                if (upd)  W[c] = fmaxf(fmaxf(red[0][c][cx], red[1][c][cx]),
                                       fmaxf(red[2][c][cx], red[3][c][cx]));
                mf[(6+c)*MLSQ + cellY*ML + cellX] = W[c];
            }
        }
        __syncthreads();
    }
    #pragma unroll
    for (int c = 0; c < CHL; c++) lm[c*MLSQ + idx] = S[c];
}

// out-of-window gmax cells, all 4 steps (cache init + done prefix)
__global__ __launch_bounds__(256) void k_gmax_out(const float* __restrict__ ws,
                                                  const int* __restrict__ dones,
                                                  const int* __restrict__ lmb,
                                                  float* __restrict__ out)
{
    int b = blockIdx.z, c = blockIdx.y;
    int idx = blockIdx.x*256 + threadIdx.x;
    int i = idx / ML, j = idx % ML;
    int y0 = lmb[b*4+0], x0 = lmb[b*4+2];
    int iy0 = y0 >> 2, ix0 = x0 >> 2;
    bool inWin = (i >= iy0) && (i < iy0 + ML/4) && (j >= ix0) && (j < ix0 + ML/4);
    if (inWin) return;
    float v = ws[WS_CACHE + ((size_t)b*6 + c)*MLSQ + idx];
    for (int t = 0; t < TT; t++) {
        if (dones[b*TT+t]) v = 0.0f;
        out[(size_t)(b*TT+t)*CHMF*MLSQ + (6+c)*MLSQ + idx] = v;
    }
}

// after loop: apply deferred done-zeroing of the global map
__global__ __launch_bounds__(256) void k_fgfix(float* __restrict__ fg,
                                               const float* __restrict__ ws,
                                               const int* __restrict__ lmb)
{
    int b = blockIdx.y;
    if (ws[WS_FLAGS + b*4 + 0] < 0.5f) return;       // no done in sequence
    bool zeroWin = ws[WS_FLAGS + b*4 + 1] > 0.5f;
    int y0 = lmb[b*4+0], y1 = lmb[b*4+1], x0 = lmb[b*4+2], x1 = lmb[b*4+3];
    float* p = fg + (size_t)b*CHL*MGSQ;
    for (size_t e = blockIdx.x*256 + threadIdx.x; e < (size_t)CHL*MGSQ;
         e += (size_t)gridDim.x*256) {
        int pix = (int)(e % MGSQ);
        int i = pix / MG, j = pix % MG;
        bool inWin = (i >= y0) && (i < y1) && (j >= x0) && (j < x1);
        if (!inWin || zeroWin) p[e] = 0.0f;
    }
}

extern "C" void kernel_launch(void* const* d_in, const int* in_sizes, int n_in,
                              void* d_out, int out_size, void* d_ws, size_t ws_size,
                              hipStream_t stream)
{
    const float* obs   = (const float*)d_in[0];
    const float* pd    = (const float*)d_in[1];
    const float* cam   = (const float*)d_in[2];
    const float* ilm   = (const float*)d_in[3];
    const float* igm   = (const float*)d_in[4];
    const float* ilp   = (const float*)d_in[5];
    const float* org   = (const float*)d_in[7];
    const int*   dones = (const int*)d_in[8];
    const int*   updg  = (const int*)d_in[9];
    const int*   lmb   = (const int*)d_in[10];
    float* out = (float*)d_out;
    float* ws  = (float*)d_ws;

    float* fl     = out + OFF_FL;
    float* fg     = out + OFF_FG;
    float* planes = ws + WS_PLANES;
    float* I2v    = ws + WS_I2;

    k_poseall<<<1, 64, 0, stream>>>(pd, ilp, org, lmb, dones, updg, out, ws);
    k_prep<<<dim3(75, BB*TT), 256, 0, stream>>>(obs, cam, ws);
    k_splat2<<<dim3(BB*TT, NPART, NGRP), 256, 0, stream>>>(ws, planes);
    k_gmaxinit2<<<dim3(225, 6, BB), 256, 0, stream>>>(igm, fg, ws);
    k_copy16<<<4096, 256, 0, stream>>>(igm, fg);
    k_gs<<<dim3(225, NPL, BB*TT), 256, 0, stream>>>(planes, ws, I2v);
    k_updl_all<<<dim3(4, 60, BB), 256, 0, stream>>>(I2v, ws, ilm, dones, updg, lmb, fl, fg, out);
    k_gmax_out<<<dim3(225, 6, BB), 256, 0, stream>>>(ws, dones, lmb, out);
    k_fgfix<<<dim3(1024, BB), 256, 0, stream>>>(fg, ws, lmb);
}